// Round 1
// baseline (558.907 us; speedup 1.0000x reference)
//
#include <hip/hip_runtime.h>

// ---- types ----
typedef __bf16 bf16x8 __attribute__((ext_vector_type(8)));
typedef __bf16 bf16x4 __attribute__((ext_vector_type(4)));
typedef float  f32x4  __attribute__((ext_vector_type(4)));

#define MFMA16 __builtin_amdgcn_mfma_f32_16x16x32_bf16

__device__ __forceinline__ float fsig(float x)  { return 1.f / (1.f + __expf(-x)); }
__device__ __forceinline__ float ftanh(float x) { return 1.f - 2.f / (__expf(2.f * x) + 1.f); }

// Problem constants
// B=512, T=20, D=1024, H=1024, 4H=4096. Only LSTM layer 1 is live (layer 0 is dead code).

// ---- convert layer-1 weights + W1 to bf16, bias_sum = b_ih[1]+b_hh[1] ----
__global__ __launch_bounds__(256) void convert_weights(
    const float* __restrict__ Wih, const float* __restrict__ Whh,
    const float* __restrict__ W1,  const float* __restrict__ bih,
    const float* __restrict__ bhh,
    __bf16* __restrict__ Wih1, __bf16* __restrict__ Whh1,
    __bf16* __restrict__ W1b,  float* __restrict__ bsum)
{
    const size_t L1 = 4096UL * 1024UL;
    size_t i = (size_t)blockIdx.x * 256 + threadIdx.x;   // 0 .. 1048575
    float4 a = *(const float4*)(Wih + L1 + i * 4);
    float4 b = *(const float4*)(Whh + L1 + i * 4);
    bf16x4 av = { (__bf16)a.x, (__bf16)a.y, (__bf16)a.z, (__bf16)a.w };
    bf16x4 bv = { (__bf16)b.x, (__bf16)b.y, (__bf16)b.z, (__bf16)b.w };
    *(bf16x4*)(Wih1 + i * 4) = av;
    *(bf16x4*)(Whh1 + i * 4) = bv;
    W1b[i] = (__bf16)W1[i];
    if (i < 4096) bsum[i] = bih[4096 + i] + bhh[4096 + i];
}

// ---- gather: xbf[t*512+b][0:512]=rel_emb[rel[b,t]], [512:1024]=ent_emb[ent[b,t]] ----
__global__ __launch_bounds__(256) void gather_x(
    const int* __restrict__ ent, const int* __restrict__ rel,
    const float* __restrict__ ent_emb, const float* __restrict__ rel_emb,
    __bf16* __restrict__ xbf)
{
    int bid = blockIdx.x;              // b*20 + t
    int b = bid / 20, t = bid - b * 20;
    int tid = threadIdx.x;
    int col = (tid & 127) * 4;
    const float* src = (tid < 128)
        ? (rel_emb + (size_t)rel[bid] * 512 + col)
        : (ent_emb + (size_t)ent[bid] * 512 + col);
    float4 v = *(const float4*)src;
    bf16x4 o = { (__bf16)v.x, (__bf16)v.y, (__bf16)v.z, (__bf16)v.w };
    int outcol = (tid < 128) ? col : (512 + col);
    *(bf16x4*)(xbf + (size_t)(t * 512 + b) * 1024 + outcol) = o;
}

// ---- generic bf16 MFMA GEMM: C[M,N] = A[M,K] @ B[N,K]^T + bias, optional ReLU ----
// 128x128 tile, BK=64, 4 waves (each 64x64), reg-staged LDS with next-tile prefetch.
template<bool RELU>
__global__ __launch_bounds__(256) void gemm_bias(
    const __bf16* __restrict__ A, const __bf16* __restrict__ B,
    const float* __restrict__ bias, __bf16* __restrict__ C,
    int M, int N, int K)
{
    __shared__ __bf16 As[128 * 64];
    __shared__ __bf16 Bs[128 * 64];
    const int tid = threadIdx.x;
    const int w = tid >> 6, lane = tid & 63;
    const int m0 = blockIdx.x * 128, n0 = blockIdx.y * 128;
    const int wr = (w >> 1) * 64, wc = (w & 1) * 64;
    const int srow = w * 32 + (lane >> 3);   // staging row (+j*8)
    const int scol = (lane & 7) * 8;

    f32x4 acc[4][4] = {};
    bf16x8 ar[4], br[4];

#pragma unroll
    for (int j = 0; j < 4; ++j) {
        ar[j] = *(const bf16x8*)(A + (size_t)(m0 + srow + j * 8) * K + scol);
        br[j] = *(const bf16x8*)(B + (size_t)(n0 + srow + j * 8) * K + scol);
    }
    for (int k0 = 0; k0 < K; k0 += 64) {
        __syncthreads();
#pragma unroll
        for (int j = 0; j < 4; ++j) {
            *(bf16x8*)&As[(w * 4 + j) * 512 + lane * 8] = ar[j];
            *(bf16x8*)&Bs[(w * 4 + j) * 512 + lane * 8] = br[j];
        }
        __syncthreads();
        if (k0 + 64 < K) {
#pragma unroll
            for (int j = 0; j < 4; ++j) {
                ar[j] = *(const bf16x8*)(A + (size_t)(m0 + srow + j * 8) * K + k0 + 64 + scol);
                br[j] = *(const bf16x8*)(B + (size_t)(n0 + srow + j * 8) * K + k0 + 64 + scol);
            }
        }
#pragma unroll
        for (int ks = 0; ks < 2; ++ks) {
            const int ko = ks * 32 + (lane >> 4) * 8;
            bf16x8 af[4], bb[4];
#pragma unroll
            for (int i = 0; i < 4; ++i)
                af[i] = *(const bf16x8*)&As[(wr + i * 16 + (lane & 15)) * 64 + ko];
#pragma unroll
            for (int j = 0; j < 4; ++j)
                bb[j] = *(const bf16x8*)&Bs[(wc + j * 16 + (lane & 15)) * 64 + ko];
#pragma unroll
            for (int i = 0; i < 4; ++i)
#pragma unroll
                for (int j = 0; j < 4; ++j)
                    acc[i][j] = MFMA16(af[i], bb[j], acc[i][j], 0, 0, 0);
        }
    }
    const int rbase = m0 + wr + (lane >> 4) * 4;
    const int cbase = n0 + wc + (lane & 15);
#pragma unroll
    for (int j = 0; j < 4; ++j) {
        const int col = cbase + j * 16;
        const float bv = bias[col];
#pragma unroll
        for (int i = 0; i < 4; ++i)
#pragma unroll
            for (int r = 0; r < 4; ++r) {
                float v = acc[i][j][r] + bv;
                if (RELU) v = fmaxf(v, 0.f);
                C[(size_t)(rbase + i * 16 + r) * N + col] = (__bf16)v;
            }
    }
}

// ---- fused recurrent step: g = h@Whh^T (+Xg slice), gates, c/h update, sel capture ----
// Block tile: 64 batch rows x (4 gates x 32 channels). Tile col c -> gate c>>5,
// channel j0+(c&31) -> Whh row (c>>5)*1024 + j0 + (c&31).  Each wave: 16 rows x 128 cols
// (8 col-frags), so each lane holds gi,gf,gg,go for the same (b,ch) in-register.
__global__ __launch_bounds__(256) void lstm_step(
    const __bf16* __restrict__ h_in, const __bf16* __restrict__ Whh,
    const __bf16* __restrict__ Xg, float* __restrict__ cst,
    __bf16* __restrict__ h_out, __bf16* __restrict__ sel,
    const int* __restrict__ dlen, int t)
{
    __shared__ __bf16 As[64 * 64];
    __shared__ __bf16 Bs[128 * 64];
    const int tid = threadIdx.x;
    const int w = tid >> 6, lane = tid & 63;
    const int m0 = blockIdx.x * 64;        // batch-row block
    const int j0 = blockIdx.y * 32;        // channel block
    const int scol = (lane & 7) * 8;
    const int arow = w * 16 + (lane >> 3); // A staging row (+j*8)
    const int brow = w * 32 + (lane >> 3); // B staging row (+j*8)

    f32x4 acc[8] = {};
    bf16x8 ar[2], br[4];

#pragma unroll
    for (int j = 0; j < 2; ++j)
        ar[j] = *(const bf16x8*)(h_in + (size_t)(m0 + arow + j * 8) * 1024 + scol);
#pragma unroll
    for (int j = 0; j < 4; ++j) {
        int r = brow + j * 8;
        int R = (r >> 5) * 1024 + j0 + (r & 31);
        br[j] = *(const bf16x8*)(Whh + (size_t)R * 1024 + scol);
    }
    for (int k0 = 0; k0 < 1024; k0 += 64) {
        __syncthreads();
#pragma unroll
        for (int j = 0; j < 2; ++j)
            *(bf16x8*)&As[(w * 2 + j) * 512 + lane * 8] = ar[j];
#pragma unroll
        for (int j = 0; j < 4; ++j)
            *(bf16x8*)&Bs[(w * 4 + j) * 512 + lane * 8] = br[j];
        __syncthreads();
        if (k0 + 64 < 1024) {
#pragma unroll
            for (int j = 0; j < 2; ++j)
                ar[j] = *(const bf16x8*)(h_in + (size_t)(m0 + arow + j * 8) * 1024 + k0 + 64 + scol);
#pragma unroll
            for (int j = 0; j < 4; ++j) {
                int r = brow + j * 8;
                int R = (r >> 5) * 1024 + j0 + (r & 31);
                br[j] = *(const bf16x8*)(Whh + (size_t)R * 1024 + k0 + 64 + scol);
            }
        }
#pragma unroll
        for (int ks = 0; ks < 2; ++ks) {
            const int ko = ks * 32 + (lane >> 4) * 8;
            bf16x8 av = *(const bf16x8*)&As[(w * 16 + (lane & 15)) * 64 + ko];
#pragma unroll
            for (int n = 0; n < 8; ++n) {
                bf16x8 bv = *(const bf16x8*)&Bs[(n * 16 + (lane & 15)) * 64 + ko];
                acc[n] = MFMA16(av, bv, acc[n], 0, 0, 0);
            }
        }
    }
    // epilogue: frag n -> gate n>>1, half n&1; lane col = lane&15; rows (lane>>4)*4+r
    const int rb = m0 + w * 16 + (lane >> 4) * 4;
#pragma unroll
    for (int half = 0; half < 2; ++half) {
        const int ch = j0 + half * 16 + (lane & 15);
#pragma unroll
        for (int r = 0; r < 4; ++r) {
            const int b = rb + r;
            const __bf16* xg = Xg + (size_t)(t * 512 + b) * 4096 + ch;
            float gi = acc[0 + half][r] + (float)xg[0];
            float gf = acc[2 + half][r] + (float)xg[1024];
            float gg = acc[4 + half][r] + (float)xg[2048];
            float go = acc[6 + half][r] + (float)xg[3072];
            const size_t ix = (size_t)b * 1024 + ch;
            float cn = fsig(gf) * cst[ix] + fsig(gi) * ftanh(gg);
            cst[ix] = cn;
            float hv = fsig(go) * ftanh(cn);
            h_out[ix] = (__bf16)hv;
            if (dlen[b] == t + 1) sel[ix] = (__bf16)hv;
        }
    }
}

// ---- final tiny layer: out[b,o] = relu(sum_k y1[b,k]*W2[o,k] + b2[o]) ----
__global__ __launch_bounds__(256) void mlp2(
    const __bf16* __restrict__ y1, const float* __restrict__ W2,
    const float* __restrict__ b2, float* __restrict__ out)
{
    int b = blockIdx.x, tid = threadIdx.x;
    float s0 = 0.f, s1 = 0.f;
    for (int k = tid; k < 1024; k += 256) {
        float v = (float)y1[(size_t)b * 1024 + k];
        s0 += v * W2[k];
        s1 += v * W2[1024 + k];
    }
#pragma unroll
    for (int o = 32; o > 0; o >>= 1) {
        s0 += __shfl_down(s0, o);
        s1 += __shfl_down(s1, o);
    }
    __shared__ float red[8];
    if ((tid & 63) == 0) { red[(tid >> 6) * 2] = s0; red[(tid >> 6) * 2 + 1] = s1; }
    __syncthreads();
    if (tid == 0) {
        float a0 = red[0] + red[2] + red[4] + red[6] + b2[0];
        float a1 = red[1] + red[3] + red[5] + red[7] + b2[1];
        out[b * 2 + 0] = fmaxf(a0, 0.f);
        out[b * 2 + 1] = fmaxf(a1, 0.f);
    }
}

extern "C" void kernel_launch(void* const* d_in, const int* in_sizes, int n_in,
                              void* d_out, int out_size, void* d_ws, size_t ws_size,
                              hipStream_t stream) {
    const int*   ent     = (const int*)d_in[0];
    const int*   rel     = (const int*)d_in[1];
    const int*   dlen    = (const int*)d_in[3];
    const float* ent_emb = (const float*)d_in[4];
    const float* rel_emb = (const float*)d_in[5];
    const float* Wih     = (const float*)d_in[6];
    const float* Whh     = (const float*)d_in[7];
    const float* bih     = (const float*)d_in[8];
    const float* bhh     = (const float*)d_in[9];
    const float* W1      = (const float*)d_in[10];
    const float* b1      = (const float*)d_in[11];
    const float* W2      = (const float*)d_in[12];
    const float* b2      = (const float*)d_in[13];
    float* out = (float*)d_out;

    char* ws = (char*)d_ws;
    size_t off = 0;
    auto alloc = [&](size_t bytes) -> void* {
        void* p = ws + off; off += (bytes + 255) & ~(size_t)255; return p;
    };
    __bf16* xbf  = (__bf16*)alloc(10240UL * 1024 * 2);   // [T*B, 1024], row = t*512+b
    __bf16* Wih1 = (__bf16*)alloc(4096UL * 1024 * 2);
    __bf16* Whh1 = (__bf16*)alloc(4096UL * 1024 * 2);
    __bf16* W1b  = (__bf16*)alloc(1024UL * 1024 * 2);
    float*  bsum = (float*) alloc(4096UL * 4);
    __bf16* Xg   = (__bf16*)alloc(10240UL * 4096 * 2);   // [T*B, 4096]
    __bf16* hA   = (__bf16*)alloc(512UL * 1024 * 2);
    __bf16* hB   = (__bf16*)alloc(512UL * 1024 * 2);
    float*  cst  = (float*) alloc(512UL * 1024 * 4);
    __bf16* selb = (__bf16*)alloc(512UL * 1024 * 2);
    __bf16* y1b  = (__bf16*)alloc(512UL * 1024 * 2);

    convert_weights<<<dim3(4096), dim3(256), 0, stream>>>(
        Wih, Whh, W1, bih, bhh, Wih1, Whh1, W1b, bsum);
    gather_x<<<dim3(10240), dim3(256), 0, stream>>>(ent, rel, ent_emb, rel_emb, xbf);
    // Xg = x @ W_ih[1]^T + (b_ih[1] + b_hh[1]) for all 10240 rows at once
    gemm_bias<false><<<dim3(80, 32), dim3(256), 0, stream>>>(
        xbf, Wih1, bsum, Xg, 10240, 4096, 1024);

    hipMemsetAsync(hA, 0, 512UL * 1024 * 2, stream);
    hipMemsetAsync(cst, 0, 512UL * 1024 * 4, stream);

    for (int t = 0; t < 20; ++t) {
        const __bf16* hi = (t & 1) ? hB : hA;
        __bf16*       ho = (t & 1) ? hA : hB;
        lstm_step<<<dim3(8, 32), dim3(256), 0, stream>>>(
            hi, Whh1, Xg, cst, ho, selb, dlen, t);
    }

    // y1 = relu(sel @ W1^T + b1)
    gemm_bias<true><<<dim3(4, 8), dim3(256), 0, stream>>>(
        selb, W1b, b1, y1b, 512, 1024, 1024);
    mlp2<<<dim3(512), dim3(256), 0, stream>>>(y1b, W2, b2, out);
}